// Round 6
// baseline (319.869 us; speedup 1.0000x reference)
//
#include <hip/hip_runtime.h>
#include <hip/hip_bf16.h>

#define S_   3136
#define H_   16
#define D_   80
#define DP_  96        // D padded to multiple of 32 for MFMA K-dim
#define HID_ 1280

typedef short  bf16x8 __attribute__((ext_vector_type(8)));
typedef short  bf16x4 __attribute__((ext_vector_type(4)));
typedef float  f32x4  __attribute__((ext_vector_type(4)));

__device__ __forceinline__ float b2f(unsigned short u) {
    union { unsigned int i; float f; } c;
    c.i = ((unsigned int)u) << 16;
    return c.f;
}
__device__ __forceinline__ unsigned short f2b(float f) {
    union { unsigned int i; float f; } c;
    c.f = f;
    unsigned int x = c.i;
    unsigned int lsb = (x >> 16) & 1u;
    x += 0x7fffu + lsb;   // round-to-nearest-even
    return (unsigned short)(x >> 16);
}
__device__ __forceinline__ unsigned int cvt_pk_bf16(float lo, float hi) {
    unsigned int r;
    asm("v_cvt_pk_bf16_f32 %0, %1, %2" : "=v"(r) : "v"(lo), "v"(hi));
    return r;
}
__device__ __forceinline__ float exp2_hw(float x) {
    float r;
    asm("v_exp_f32 %0, %1" : "=v"(r) : "v"(x));
    return r;
}

typedef const void __attribute__((address_space(1))) GAS;
typedef void __attribute__((address_space(3))) LAS;
__device__ __forceinline__ void gl16(const void* g, void* l) {
    __builtin_amdgcn_global_load_lds((GAS*)g, (LAS*)l, 16, 0, 0);
}

// ---------------------------------------------------------------------------
// merged fp32 -> bf16 cast for x_norm / qkv_w / proj_w (one launch)
// ---------------------------------------------------------------------------
#define N4_X 1003520
#define N4_Q 1228800
#define N4_P 409600

__global__ __launch_bounds__(256)
void cast3_kernel(const float* __restrict__ x0, unsigned short* __restrict__ y0,
                  const float* __restrict__ x1, unsigned short* __restrict__ y1,
                  const float* __restrict__ x2, unsigned short* __restrict__ y2)
{
    int i = blockIdx.x * 256 + threadIdx.x;
    const float* src; unsigned short* dst;
    if (i < N4_X)               { src = x0; dst = y0; }
    else if (i < N4_X + N4_Q)   { src = x1; dst = y1; i -= N4_X; }
    else if (i < N4_X + N4_Q + N4_P) { src = x2; dst = y2; i -= N4_X + N4_Q; }
    else return;
    float4 v = ((const float4*)src)[i];
    ushort4 o;
    o.x = f2b(v.x); o.y = f2b(v.y); o.z = f2b(v.z); o.w = f2b(v.w);
    ((ushort4*)dst)[i] = o;
}

// ---------------------------------------------------------------------------
// QKV GEMM v2 — 128x128 tile, BK=32 double-buffered via global_load_lds
// (attn-proven structure): stage-early, ONE vmcnt(0)+barrier per K-step.
// LDS rows 64B (32 shorts): fragment b128 reads are naturally conflict-free
// (row parity alternates bank halves), staging writes are linear. 4 waves
// (2x2), wave 64x64 output, identical fragment/epilogue semantics to the
// previous verified kernel.
// ---------------------------------------------------------------------------
__global__ __launch_bounds__(256)
void qkv_mfma_kernel(const unsigned short* __restrict__ Ab,
                     const unsigned short* __restrict__ Wb,
                     const float* __restrict__ bias,
                     unsigned short* __restrict__ qo, unsigned short* __restrict__ ko,
                     unsigned short* __restrict__ vtb)
{
    __shared__ __align__(16) short As[2][128][32];   // 16 KB
    __shared__ __align__(16) short Bs[2][128][32];   // 16 KB
    int m0 = blockIdx.x * 128;
    int n0 = blockIdx.y * 128;
    int t = threadIdx.x;
    int wave = t >> 6, lane = t & 63, lq = lane & 15, quad = lane >> 4;
    int wr = wave >> 1, wc = wave & 1;

    // staging descriptors: instr i covers LDS rows i*16..i*16+15 (1024 B);
    // lane -> row = i*16 + (lane>>2), k-offset = (lane&3)*8 shorts.
    const unsigned short* aS[2]; const unsigned short* bS[2]; int dD[2];
    #pragma unroll
    for (int ii = 0; ii < 2; ++ii) {
        int i   = wave * 2 + ii;
        int row = i * 16 + (lane >> 2);
        int kc  = (lane & 3) * 8;
        aS[ii] = Ab + (size_t)min(m0 + row, S_ - 1) * HID_ + kc;
        bS[ii] = Wb + (size_t)(n0 + row) * HID_ + kc;
        dD[ii] = i * 1024;
    }

    #define QSTAGE(buf, kk)                                                     \
        do {                                                                    \
            _Pragma("unroll")                                                   \
            for (int ii = 0; ii < 2; ++ii) {                                    \
                gl16(aS[ii] + (kk), (char*)As + (buf) * 8192 + dD[ii]);         \
                gl16(bS[ii] + (kk), (char*)Bs + (buf) * 8192 + dD[ii]);         \
            }                                                                   \
        } while (0)

    f32x4 acc[4][4];
    #pragma unroll
    for (int i = 0; i < 4; ++i)
        #pragma unroll
        for (int j = 0; j < 4; ++j) acc[i][j] = (f32x4){0.f, 0.f, 0.f, 0.f};

    #define QCOMPUTE(buf)                                                       \
        do {                                                                    \
            bf16x8 af[4], bfr[4];                                               \
            _Pragma("unroll")                                                   \
            for (int i = 0; i < 4; ++i)                                         \
                af[i] = *(const bf16x8*)((const char*)As + (buf) * 8192         \
                        + (wr * 64 + i * 16 + lq) * 64 + quad * 16);            \
            _Pragma("unroll")                                                   \
            for (int j = 0; j < 4; ++j)                                         \
                bfr[j] = *(const bf16x8*)((const char*)Bs + (buf) * 8192        \
                        + (wc * 64 + j * 16 + lq) * 64 + quad * 16);            \
            _Pragma("unroll")                                                   \
            for (int i = 0; i < 4; ++i)                                         \
                _Pragma("unroll")                                               \
                for (int j = 0; j < 4; ++j)                                     \
                    acc[i][j] = __builtin_amdgcn_mfma_f32_16x16x32_bf16(        \
                        af[i], bfr[j], acc[i][j], 0, 0, 0);                     \
        } while (0)

    // prologue
    QSTAGE(0, 0);
    asm volatile("s_waitcnt vmcnt(0)" ::: "memory");
    __syncthreads();

    for (int kt = 0; kt < HID_; kt += 64) {
        QSTAGE(1, kt + 32);                       // kt+32 <= 1248 always valid
        QCOMPUTE(0);
        asm volatile("s_waitcnt vmcnt(0)" ::: "memory");
        __syncthreads();
        if (kt + 64 < HID_) QSTAGE(0, kt + 64);
        QCOMPUTE(1);
        asm volatile("s_waitcnt vmcnt(0)" ::: "memory");
        __syncthreads();
    }
    #undef QSTAGE
    #undef QCOMPUTE

    #pragma unroll
    for (int i = 0; i < 4; ++i)
        #pragma unroll
        for (int j = 0; j < 4; ++j)
            #pragma unroll
            for (int reg = 0; reg < 4; ++reg) {
                int row = m0 + wr * 64 + i * 16 + quad * 4 + reg;
                if (row >= S_) continue;
                int col = n0 + wc * 64 + j * 16 + lq;
                float val = acc[i][j][reg] + bias[col];
                int which = col / HID_;
                int rem   = col - which * HID_;
                int h     = rem / D_;
                int d     = rem - h * D_;
                if (which == 0)      qo[((size_t)h * S_ + row) * D_ + d] = f2b(val);
                else if (which == 1) ko[((size_t)h * S_ + row) * D_ + d] = f2b(val);
                else                 vtb[((size_t)h * D_ + d) * S_ + row] = f2b(val);
            }
}

// ---------------------------------------------------------------------------
// Proj GEMM 64x64 tiles (grid 49x20 = 980 blocks ~3.8/CU) — round-9 winner.
// ---------------------------------------------------------------------------
#define ASTR 40

__global__ __launch_bounds__(256)
void proj_mfma_kernel(const unsigned short* __restrict__ Ab,
                      const unsigned short* __restrict__ Wb,
                      const float* __restrict__ bias, const float* __restrict__ hidden,
                      float* __restrict__ out)
{
    __shared__ __align__(16) short As[64][ASTR];
    __shared__ __align__(16) short Bs[64][ASTR];
    int m0 = blockIdx.x * 64;
    int n0 = blockIdx.y * 64;
    int t = threadIdx.x;
    int wave = t >> 6, lane = t & 63, lq = lane & 15, quad = lane >> 4;
    int wr = wave >> 1, wc = wave & 1;

    int r  = t >> 2;
    int kc0 = (t & 3) << 3;
    const unsigned short* pa = Ab + (size_t)(m0 + r) * HID_ + kc0;
    const unsigned short* pb = Wb + (size_t)(n0 + r) * HID_ + kc0;
    short* sa = &As[r][kc0];
    short* sb = &Bs[r][kc0];

    const bf16x8* afp[2]; const bf16x8* bfp[2];
    #pragma unroll
    for (int i = 0; i < 2; ++i) {
        afp[i] = (const bf16x8*)&As[wr * 32 + i * 16 + lq][quad * 8];
        bfp[i] = (const bf16x8*)&Bs[wc * 32 + i * 16 + lq][quad * 8];
    }

    f32x4 acc[2][2];
    #pragma unroll
    for (int i = 0; i < 2; ++i)
        #pragma unroll
        for (int j = 0; j < 2; ++j) acc[i][j] = (f32x4){0.f, 0.f, 0.f, 0.f};

    bf16x8 va = *(const bf16x8*)(pa);
    bf16x8 vb = *(const bf16x8*)(pb);

    for (int kt = 0; kt < HID_; kt += 32) {
        __syncthreads();
        *(bf16x8*)sa = va;
        *(bf16x8*)sb = vb;
        __syncthreads();
        if (kt + 32 < HID_) {
            va = *(const bf16x8*)(pa + kt + 32);
            vb = *(const bf16x8*)(pb + kt + 32);
        }
        bf16x8 af[2], bfr[2];
        #pragma unroll
        for (int i = 0; i < 2; ++i) af[i]  = *afp[i];
        #pragma unroll
        for (int j = 0; j < 2; ++j) bfr[j] = *bfp[j];
        #pragma unroll
        for (int i = 0; i < 2; ++i)
            #pragma unroll
            for (int j = 0; j < 2; ++j)
                acc[i][j] = __builtin_amdgcn_mfma_f32_16x16x32_bf16(af[i], bfr[j], acc[i][j], 0, 0, 0);
    }

    #pragma unroll
    for (int i = 0; i < 2; ++i)
        #pragma unroll
        for (int j = 0; j < 2; ++j)
            #pragma unroll
            for (int reg = 0; reg < 4; ++reg) {
                int row = m0 + wr * 32 + i * 16 + quad * 4 + reg;
                int col = n0 + wc * 32 + j * 16 + lq;
                out[(size_t)row * HID_ + col] =
                    acc[i][j][reg] + bias[col] + hidden[(size_t)row * HID_ + col];
            }
}

// ---------------------------------------------------------------------------
// RoPE + rescale v2 — vectorized: one thread = 8 rotation pairs (16B/32B
// vector loads/stores). Reads q,k bf16 [H][S][80]; writes [H][S][96].
// ---------------------------------------------------------------------------
__global__ __launch_bounds__(256)
void rope_kernel(const unsigned short* __restrict__ q, const unsigned short* __restrict__ k,
                 const float* __restrict__ cost, const float* __restrict__ sint,
                 unsigned short* __restrict__ qb, unsigned short* __restrict__ kb)
{
    const float QSCALE = 0.11180339887498949f * 1.4426950408889634f;  // 1/sqrt(80)*log2(e)
    int idx = blockIdx.x * 256 + threadIdx.x;   // over H*S*5
    const int total = H_ * S_ * 5;
    if (idx >= total) return;
    int j  = idx % 5;
    int hs = idx / 5;
    int s  = hs % S_;
    int d0 = j * 8;
    const unsigned short* qp = q + (size_t)hs * D_ + d0;
    const unsigned short* kp = k + (size_t)hs * D_ + d0;
    unsigned short* qo = qb + (size_t)hs * DP_ + d0;
    unsigned short* ko = kb + (size_t)hs * DP_ + d0;
    const float* cp = cost + s * D_ + d0;
    const float* sp = sint + s * D_ + d0;

    bf16x8 q1 = *(const bf16x8*)(qp);
    bf16x8 q2 = *(const bf16x8*)(qp + 40);
    bf16x8 k1 = *(const bf16x8*)(kp);
    bf16x8 k2 = *(const bf16x8*)(kp + 40);
    f32x4 c1[2] = { *(const f32x4*)(cp),      *(const f32x4*)(cp + 4)  };
    f32x4 c2[2] = { *(const f32x4*)(cp + 40), *(const f32x4*)(cp + 44) };
    f32x4 s1[2] = { *(const f32x4*)(sp),      *(const f32x4*)(sp + 4)  };
    f32x4 s2[2] = { *(const f32x4*)(sp + 40), *(const f32x4*)(sp + 44) };

    bf16x8 oq1, oq2, ok1, ok2;
    #pragma unroll
    for (int e = 0; e < 8; ++e) {
        float cc1 = c1[e >> 2][e & 3], ss1 = s1[e >> 2][e & 3];
        float cc2 = c2[e >> 2][e & 3], ss2 = s2[e >> 2][e & 3];
        float x1 = b2f((unsigned short)q1[e]), x2 = b2f((unsigned short)q2[e]);
        oq1[e] = (short)f2b((x1 * cc1 - x2 * ss1) * QSCALE);
        oq2[e] = (short)f2b((x2 * cc2 + x1 * ss2) * QSCALE);
        x1 = b2f((unsigned short)k1[e]); x2 = b2f((unsigned short)k2[e]);
        ok1[e] = (short)f2b(x1 * cc1 - x2 * ss1);
        ok2[e] = (short)f2b(x2 * cc2 + x1 * ss2);
    }
    *(bf16x8*)(qo)      = oq1;
    *(bf16x8*)(qo + 40) = oq2;
    *(bf16x8*)(ko)      = ok1;
    *(bf16x8*)(ko + 40) = ok2;
    if (j == 0) {
        uint4 z = {0u, 0u, 0u, 0u};
        *(uint4*)(qo + 80) = z;
        *(uint4*)(qo + 88) = z;
        *(uint4*)(ko + 80) = z;
        *(uint4*)(ko + 88) = z;
    }
}

// ---------------------------------------------------------------------------
// Flash attention v6 — K+V LDS double-buffer, stage-early, one barrier per
// round, s_setprio around MFMA clusters, hw exp2. (measured 94 us)
// ---------------------------------------------------------------------------
#define KBUF_ 16384
#define VBUF_ 10240
#define BUF_  26624    // KBUF_ + VBUF_

__global__ __launch_bounds__(256, 3)
void attn_kernel(const unsigned short* __restrict__ Qb,
                 const unsigned short* __restrict__ Kb,
                 const unsigned short* __restrict__ Vtb,
                 unsigned short* __restrict__ attnb)
{
    __shared__ __align__(16) unsigned char smem[2 * BUF_];

    int h   = blockIdx.y;
    int qb0 = blockIdx.x * 64;
    int t      = threadIdx.x;
    int wave   = t >> 6;
    int lane   = t & 63;
    int lq     = lane & 15;
    int quad   = lane >> 4;
    int qh     = wave & 1;
    int stripe = wave >> 1;
    int Q0     = qb0 + qh * 32;
    int swz    = (lq & 7) << 4;

    // Q fragments: 2 q-tiles x 3 k-chunks (B-operand of mfma(K,Q))
    bf16x8 qf[2][3];
    #pragma unroll
    for (int qt = 0; qt < 2; ++qt)
        #pragma unroll
        for (int kc = 0; kc < 3; ++kc)
            qf[qt][kc] = *(const bf16x8*)(Qb + ((size_t)h * S_ + Q0 + qt * 16 + lq) * DP_ + kc * 32 + quad * 8);

    f32x4 O[2][5];
    #pragma unroll
    for (int qt = 0; qt < 2; ++qt)
        #pragma unroll
        for (int dt = 0; dt < 5; ++dt) O[qt][dt] = (f32x4){0.f, 0.f, 0.f, 0.f};
    float l_acc[2] = {0.f, 0.f};

    // ---- staging descriptors (round-0 sources; advance by r * stride)
    const unsigned char* kS[4]; int kD[4];
    #pragma unroll
    for (int ii = 0; ii < 4; ++ii) {
        int i  = wave * 4 + ii;
        int rl = i * 4 + (lane >> 4);          // LDS row 0..63 == k-row within round
        kS[ii] = (const unsigned char*)(Kb + ((size_t)h * S_ + rl) * DP_)
               + (((lane & 15) * 16) ^ ((rl & 7) << 4));
        kD[ii] = i * 1024;
    }
    const unsigned char* vS[3]; int vD[3];
    int nv = (wave < 2) ? 3 : 2;
    #pragma unroll
    for (int jj = 0; jj < 3; ++jj) {
        int j = (jj < 2) ? (wave + jj * 4) : (8 + wave);
        int d = j * 8 + (lane >> 3);           // 0..79 (for used instrs)
        vS[jj] = (const unsigned char*)(Vtb + (size_t)(h * D_ + d) * S_)
               + (((lane & 7) * 16) ^ ((d & 7) << 4));
        vD[jj] = KBUF_ + j * 1024;
    }

    #define STAGE(bufoff, rr)                                                   \
        do {                                                                    \
            size_t kadv = (size_t)(rr) * (64 * DP_ * 2);                        \
            size_t vadv = (size_t)(rr) * 128;                                   \
            _Pragma("unroll")                                                   \
            for (int ii = 0; ii < 4; ++ii)                                      \
                gl16(kS[ii] + kadv, smem + (bufoff) + kD[ii]);                  \
            _Pragma("unroll")                                                   \
            for (int jj = 0; jj < 3; ++jj)                                      \
                if (jj < nv) gl16(vS[jj] + vadv, smem + (bufoff) + vD[jj]);     \
        } while (0)

    // ---- prologue: stage round 0
    STAGE(0, 0);
    asm volatile("s_waitcnt vmcnt(0)" ::: "memory");
    __syncthreads();

    int cur = 0;
    for (int r = 0; r < 49; ++r) {
        if (r < 48) STAGE(cur ^ BUF_, r + 1);

        const unsigned char* Kbase = smem + cur;
        const unsigned char* Vbase = Kbase + KBUF_;

        // ---- QK^T (swapped: mfma(K,Q)); own 32-k stripe = 2 kt tiles
        f32x4 sc[2][2];
        __builtin_amdgcn_s_setprio(1);
        #pragma unroll
        for (int kt = 0; kt < 2; ++kt) {
            const unsigned char* kbp = Kbase + (stripe * 32 + kt * 16 + lq) * 256;
            bf16x8 kf0 = *(const bf16x8*)(kbp + ((  0 + quad * 16) ^ swz));
            bf16x8 kf1 = *(const bf16x8*)(kbp + (( 64 + quad * 16) ^ swz));
            bf16x8 kf2 = *(const bf16x8*)(kbp + ((128 + quad * 16) ^ swz));
            #pragma unroll
            for (int qt = 0; qt < 2; ++qt) {
                f32x4 a = (f32x4){0.f, 0.f, 0.f, 0.f};
                a = __builtin_amdgcn_mfma_f32_16x16x32_bf16(kf0, qf[qt][0], a, 0, 0, 0);
                a = __builtin_amdgcn_mfma_f32_16x16x32_bf16(kf1, qf[qt][1], a, 0, 0, 0);
                a = __builtin_amdgcn_mfma_f32_16x16x32_bf16(kf2, qf[qt][2], a, 0, 0, 0);
                sc[qt][kt] = a;
            }
        }
        __builtin_amdgcn_s_setprio(0);

        // ---- softmax numerator, fully in-register (hw exp2)
        union PaU { bf16x8 v8; unsigned int d[4]; } pa[2];
        #pragma unroll
        for (int qt = 0; qt < 2; ++qt) {
            float e00 = exp2_hw(sc[qt][0][0]), e01 = exp2_hw(sc[qt][0][1]);
            float e02 = exp2_hw(sc[qt][0][2]), e03 = exp2_hw(sc[qt][0][3]);
            float e10 = exp2_hw(sc[qt][1][0]), e11 = exp2_hw(sc[qt][1][1]);
            float e12 = exp2_hw(sc[qt][1][2]), e13 = exp2_hw(sc[qt][1][3]);
            l_acc[qt] += ((e00 + e01) + (e02 + e03)) + ((e10 + e11) + (e12 + e13));
            pa[qt].d[0] = cvt_pk_bf16(e00, e01);
            pa[qt].d[1] = cvt_pk_bf16(e02, e03);
            pa[qt].d[2] = cvt_pk_bf16(e10, e11);
            pa[qt].d[3] = cvt_pk_bf16(e12, e13);
        }

        // ---- PV with permuted K-dim: k_eff(quad,j) = stripe*32+(j>>2)*16+quad*4+(j&3)
        __builtin_amdgcn_s_setprio(1);
        #pragma unroll
        for (int dt = 0; dt < 5; ++dt) {
            const unsigned char* vbp = Vbase + (dt * 16 + lq) * 128;
            union { bf16x8 v8; bf16x4 v4[2]; } vv;
            vv.v4[0] = *(const bf16x4*)(vbp + ((stripe * 64 +      quad * 8) ^ swz));
            vv.v4[1] = *(const bf16x4*)(vbp + ((stripe * 64 + 32 + quad * 8) ^ swz));
            #pragma unroll
            for (int qt = 0; qt < 2; ++qt)
                O[qt][dt] = __builtin_amdgcn_mfma_f32_16x16x32_bf16(pa[qt].v8, vv.v8, O[qt][dt], 0, 0, 0);
        }
        __builtin_amdgcn_s_setprio(0);

        asm volatile("s_waitcnt vmcnt(0)" ::: "memory");
        __syncthreads();
        cur ^= BUF_;
    }
    #undef STAGE

    // ---- epilogue: cross-quad l reduce, cross-stripe O/l reduce via LDS
    float lr[2];
    #pragma unroll
    for (int qt = 0; qt < 2; ++qt) {
        float l = l_acc[qt];
        l += __shfl_xor(l, 16);
        l += __shfl_xor(l, 32);
        lr[qt] = l;                       // quad-uniform denom partial for (qt,lq)
    }
    f32x4* Of = (f32x4*)smem;             // [qh*2+qt][dt][lane]
    float* Lf = (float*)(smem + 20480);   // [qh*2+qt][16]
    if (stripe == 1) {
        #pragma unroll
        for (int qt = 0; qt < 2; ++qt) {
            #pragma unroll
            for (int dt = 0; dt < 5; ++dt)
                Of[((qh * 2 + qt) * 5 + dt) * 64 + lane] = O[qt][dt];
            if (lane < 16) Lf[(qh * 2 + qt) * 16 + lane] = lr[qt];
        }
    }
    __syncthreads();
    if (stripe == 0) {
        #pragma unroll
        for (int qt = 0; qt < 2; ++qt) {
            float ltot = lr[qt] + Lf[(qh * 2 + qt) * 16 + lq];
            #pragma unroll
            for (int dt = 0; dt < 5; ++dt)
                O[qt][dt] += Of[((qh * 2 + qt) * 5 + dt) * 64 + lane];
            #pragma unroll
            for (int reg = 0; reg < 4; ++reg) {
                float l = __shfl(ltot, quad * 4 + reg, 16);
                float linv = 1.0f / l;
                int s = Q0 + qt * 16 + quad * 4 + reg;
                unsigned short* orow = attnb + (size_t)s * HID_ + h * D_;
                #pragma unroll
                for (int dt = 0; dt < 5; ++dt)
                    orow[dt * 16 + lq] = f2b(O[qt][dt][reg] * linv);
            }
        }
    }
}

// ---------------------------------------------------------------------------
extern "C" void kernel_launch(void* const* d_in, const int* in_sizes, int n_in,
                              void* d_out, int out_size, void* d_ws, size_t ws_size,
                              hipStream_t stream)
{
    const float* hidden = (const float*)d_in[0];
    const float* x_norm = (const float*)d_in[1];
    const float* qkv_w  = (const float*)d_in[2];
    const float* qkv_b  = (const float*)d_in[3];
    const float* proj_w = (const float*)d_in[4];
    const float* proj_b = (const float*)d_in[5];
    const float* cost   = (const float*)d_in[6];
    const float* sint   = (const float*)d_in[7];
    float* out = (float*)d_out;

    unsigned short* w      = (unsigned short*)d_ws;
    unsigned short* qbuf   = w;                       // [H][S][80]  pre-rope q
    unsigned short* kbuf   = qbuf + 4014080;          // [H][S][80]  pre-rope k
    unsigned short* vtb    = kbuf + 4014080;          // [H][80][S]  v transposed (+16-row pad)
    unsigned short* kbb    = vtb + 4064256;           // [H][S][96]  roped k
    unsigned short* xb     = kbb + 4816896;           // [S][HID]    x_norm bf16
    unsigned short* wqkvb  = xb + 4014080;            // [3840][HID] qkv_w bf16
    unsigned short* wprojb = wqkvb + 4915200;         // [HID][HID]  proj_w bf16
    unsigned short* qbb    = wqkvb;                   // alias: roped q (wqkvb dead after qkv gemm)
    unsigned short* abuf   = qbuf;                    // alias: attn out (qbuf dead after rope)

    cast3_kernel<<<(N4_X + N4_Q + N4_P + 255) / 256, 256, 0, stream>>>(
        x_norm, xb, qkv_w, wqkvb, proj_w, wprojb);

    qkv_mfma_kernel<<<dim3(25, 30), 256, 0, stream>>>(xb, wqkvb, qkv_b, qbuf, kbuf, vtb);
    rope_kernel<<<(H_ * S_ * 5 + 255) / 256, 256, 0, stream>>>(qbuf, kbuf, cost, sint, qbb, kbb);
    attn_kernel<<<dim3(S_ / 64, H_), 256, 0, stream>>>(qbb, kbb, vtb, abuf);
    proj_mfma_kernel<<<dim3(49, 20), 256, 0, stream>>>(abuf, wprojb, proj_b, hidden, out);
}

// Round 7
// 301.384 us; speedup vs baseline: 1.0613x; 1.0613x over previous
//
#include <hip/hip_runtime.h>
#include <hip/hip_bf16.h>

#define S_   3136
#define H_   16
#define D_   80
#define DP_  96        // D padded to multiple of 32 for MFMA K-dim
#define HID_ 1280

typedef short  bf16x8 __attribute__((ext_vector_type(8)));
typedef short  bf16x4 __attribute__((ext_vector_type(4)));
typedef float  f32x4  __attribute__((ext_vector_type(4)));

__device__ __forceinline__ float b2f(unsigned short u) {
    union { unsigned int i; float f; } c;
    c.i = ((unsigned int)u) << 16;
    return c.f;
}
__device__ __forceinline__ unsigned short f2b(float f) {
    union { unsigned int i; float f; } c;
    c.f = f;
    unsigned int x = c.i;
    unsigned int lsb = (x >> 16) & 1u;
    x += 0x7fffu + lsb;   // round-to-nearest-even
    return (unsigned short)(x >> 16);
}
__device__ __forceinline__ unsigned int cvt_pk_bf16(float lo, float hi) {
    unsigned int r;
    asm("v_cvt_pk_bf16_f32 %0, %1, %2" : "=v"(r) : "v"(lo), "v"(hi));
    return r;
}
__device__ __forceinline__ float exp2_hw(float x) {
    float r;
    asm("v_exp_f32 %0, %1" : "=v"(r) : "v"(x));
    return r;
}

typedef const void __attribute__((address_space(1))) GAS;
typedef void __attribute__((address_space(3))) LAS;
__device__ __forceinline__ void gl16(const void* g, void* l) {
    __builtin_amdgcn_global_load_lds((GAS*)g, (LAS*)l, 16, 0, 0);
}

// ---------------------------------------------------------------------------
// merged fp32 -> bf16 cast for x_norm / qkv_w / proj_w (one launch)
// ---------------------------------------------------------------------------
#define N4_X 1003520
#define N4_Q 1228800
#define N4_P 409600

__global__ __launch_bounds__(256)
void cast3_kernel(const float* __restrict__ x0, unsigned short* __restrict__ y0,
                  const float* __restrict__ x1, unsigned short* __restrict__ y1,
                  const float* __restrict__ x2, unsigned short* __restrict__ y2)
{
    int i = blockIdx.x * 256 + threadIdx.x;
    const float* src; unsigned short* dst;
    if (i < N4_X)               { src = x0; dst = y0; }
    else if (i < N4_X + N4_Q)   { src = x1; dst = y1; i -= N4_X; }
    else if (i < N4_X + N4_Q + N4_P) { src = x2; dst = y2; i -= N4_X + N4_Q; }
    else return;
    float4 v = ((const float4*)src)[i];
    ushort4 o;
    o.x = f2b(v.x); o.y = f2b(v.y); o.z = f2b(v.z); o.w = f2b(v.w);
    ((ushort4*)dst)[i] = o;
}

// ---------------------------------------------------------------------------
// QKV GEMM (round-5 proven): 128x128 tile, BK=64 via DOUBLE-SLAB LDS,
// register-staged with full-iteration prefetch distance. 4 waves (2x2).
// ---------------------------------------------------------------------------
#define ASTR 40

__global__ __launch_bounds__(256)
void qkv_mfma_kernel(const unsigned short* __restrict__ Ab,
                     const unsigned short* __restrict__ Wb,
                     const float* __restrict__ bias,
                     unsigned short* __restrict__ qo, unsigned short* __restrict__ ko,
                     unsigned short* __restrict__ vtb)
{
    __shared__ __align__(16) short As[2][128][ASTR];
    __shared__ __align__(16) short Bs[2][128][ASTR];
    int m0 = blockIdx.x * 128;
    int n0 = blockIdx.y * 128;
    int t = threadIdx.x;
    int wave = t >> 6, lane = t & 63, lq = lane & 15, quad = lane >> 4;
    int wr = wave >> 1, wc = wave & 1;

    int r0  = t >> 2;
    int r1  = r0 + 64;
    int kc0 = (t & 3) << 3;
    const unsigned short* pa0 = Ab + (size_t)min(m0 + r0, S_ - 1) * HID_ + kc0;
    const unsigned short* pa1 = Ab + (size_t)min(m0 + r1, S_ - 1) * HID_ + kc0;
    const unsigned short* pb0 = Wb + (size_t)(n0 + r0) * HID_ + kc0;
    const unsigned short* pb1 = Wb + (size_t)(n0 + r1) * HID_ + kc0;

    const bf16x8* afp[2][4]; const bf16x8* bfp[2][4];
    #pragma unroll
    for (int s = 0; s < 2; ++s)
        #pragma unroll
        for (int i = 0; i < 4; ++i) {
            afp[s][i] = (const bf16x8*)&As[s][wr * 64 + i * 16 + lq][quad * 8];
            bfp[s][i] = (const bf16x8*)&Bs[s][wc * 64 + i * 16 + lq][quad * 8];
        }

    f32x4 acc[4][4];
    #pragma unroll
    for (int i = 0; i < 4; ++i)
        #pragma unroll
        for (int j = 0; j < 4; ++j) acc[i][j] = (f32x4){0.f, 0.f, 0.f, 0.f};

    bf16x8 va[2][2], vb[2][2];   // [slab][row-half]
    #pragma unroll
    for (int s = 0; s < 2; ++s) {
        va[s][0] = *(const bf16x8*)(pa0 + s * 32);
        va[s][1] = *(const bf16x8*)(pa1 + s * 32);
        vb[s][0] = *(const bf16x8*)(pb0 + s * 32);
        vb[s][1] = *(const bf16x8*)(pb1 + s * 32);
    }

    for (int kt = 0; kt < HID_; kt += 64) {
        __syncthreads();
        #pragma unroll
        for (int s = 0; s < 2; ++s) {
            *(bf16x8*)&As[s][r0][kc0] = va[s][0];
            *(bf16x8*)&As[s][r1][kc0] = va[s][1];
            *(bf16x8*)&Bs[s][r0][kc0] = vb[s][0];
            *(bf16x8*)&Bs[s][r1][kc0] = vb[s][1];
        }
        __syncthreads();
        if (kt + 64 < HID_) {
            #pragma unroll
            for (int s = 0; s < 2; ++s) {
                va[s][0] = *(const bf16x8*)(pa0 + kt + 64 + s * 32);
                va[s][1] = *(const bf16x8*)(pa1 + kt + 64 + s * 32);
                vb[s][0] = *(const bf16x8*)(pb0 + kt + 64 + s * 32);
                vb[s][1] = *(const bf16x8*)(pb1 + kt + 64 + s * 32);
            }
        }
        #pragma unroll
        for (int s = 0; s < 2; ++s) {
            bf16x8 af[4], bfr[4];
            #pragma unroll
            for (int i = 0; i < 4; ++i) af[i]  = *afp[s][i];
            #pragma unroll
            for (int j = 0; j < 4; ++j) bfr[j] = *bfp[s][j];
            #pragma unroll
            for (int i = 0; i < 4; ++i)
                #pragma unroll
                for (int j = 0; j < 4; ++j)
                    acc[i][j] = __builtin_amdgcn_mfma_f32_16x16x32_bf16(af[i], bfr[j], acc[i][j], 0, 0, 0);
        }
    }

    #pragma unroll
    for (int i = 0; i < 4; ++i)
        #pragma unroll
        for (int j = 0; j < 4; ++j)
            #pragma unroll
            for (int reg = 0; reg < 4; ++reg) {
                int row = m0 + wr * 64 + i * 16 + quad * 4 + reg;
                if (row >= S_) continue;
                int col = n0 + wc * 64 + j * 16 + lq;
                float val = acc[i][j][reg] + bias[col];
                int which = col / HID_;
                int rem   = col - which * HID_;
                int h     = rem / D_;
                int d     = rem - h * D_;
                if (which == 0)      qo[((size_t)h * S_ + row) * D_ + d] = f2b(val);
                else if (which == 1) ko[((size_t)h * S_ + row) * D_ + d] = f2b(val);
                else                 vtb[((size_t)h * D_ + d) * S_ + row] = f2b(val);
            }
}

// ---------------------------------------------------------------------------
// Proj GEMM v2 — 64x64 tile, QUAD-SLAB BK=128 (same proven per-slab pattern
// as qkv): barrier-pairs 80 -> 20, per-iter compute 4 -> 16 MFMA, register
// prefetch a full iteration ahead. LDS 41 KB -> still ~3.8 blocks/CU.
// ---------------------------------------------------------------------------
__global__ __launch_bounds__(256)
void proj_mfma_kernel(const unsigned short* __restrict__ Ab,
                      const unsigned short* __restrict__ Wb,
                      const float* __restrict__ bias, const float* __restrict__ hidden,
                      float* __restrict__ out)
{
    __shared__ __align__(16) short As[4][64][ASTR];
    __shared__ __align__(16) short Bs[4][64][ASTR];
    int m0 = blockIdx.x * 64;
    int n0 = blockIdx.y * 64;
    int t = threadIdx.x;
    int wave = t >> 6, lane = t & 63, lq = lane & 15, quad = lane >> 4;
    int wr = wave >> 1, wc = wave & 1;

    int r  = t >> 2;
    int kc0 = (t & 3) << 3;
    const unsigned short* pa = Ab + (size_t)(m0 + r) * HID_ + kc0;
    const unsigned short* pb = Wb + (size_t)(n0 + r) * HID_ + kc0;

    const bf16x8* afp[4][2]; const bf16x8* bfp[4][2];
    #pragma unroll
    for (int s = 0; s < 4; ++s)
        #pragma unroll
        for (int i = 0; i < 2; ++i) {
            afp[s][i] = (const bf16x8*)&As[s][wr * 32 + i * 16 + lq][quad * 8];
            bfp[s][i] = (const bf16x8*)&Bs[s][wc * 32 + i * 16 + lq][quad * 8];
        }

    f32x4 acc[2][2];
    #pragma unroll
    for (int i = 0; i < 2; ++i)
        #pragma unroll
        for (int j = 0; j < 2; ++j) acc[i][j] = (f32x4){0.f, 0.f, 0.f, 0.f};

    bf16x8 va[4], vb[4];
    #pragma unroll
    for (int s = 0; s < 4; ++s) {
        va[s] = *(const bf16x8*)(pa + s * 32);
        vb[s] = *(const bf16x8*)(pb + s * 32);
    }

    for (int kt = 0; kt < HID_; kt += 128) {
        __syncthreads();
        #pragma unroll
        for (int s = 0; s < 4; ++s) {
            *(bf16x8*)&As[s][r][kc0] = va[s];
            *(bf16x8*)&Bs[s][r][kc0] = vb[s];
        }
        __syncthreads();
        if (kt + 128 < HID_) {
            #pragma unroll
            for (int s = 0; s < 4; ++s) {
                va[s] = *(const bf16x8*)(pa + kt + 128 + s * 32);
                vb[s] = *(const bf16x8*)(pb + kt + 128 + s * 32);
            }
        }
        #pragma unroll
        for (int s = 0; s < 4; ++s) {
            bf16x8 af[2], bfr[2];
            #pragma unroll
            for (int i = 0; i < 2; ++i) af[i]  = *afp[s][i];
            #pragma unroll
            for (int j = 0; j < 2; ++j) bfr[j] = *bfp[s][j];
            #pragma unroll
            for (int i = 0; i < 2; ++i)
                #pragma unroll
                for (int j = 0; j < 2; ++j)
                    acc[i][j] = __builtin_amdgcn_mfma_f32_16x16x32_bf16(af[i], bfr[j], acc[i][j], 0, 0, 0);
        }
    }

    #pragma unroll
    for (int i = 0; i < 2; ++i)
        #pragma unroll
        for (int j = 0; j < 2; ++j)
            #pragma unroll
            for (int reg = 0; reg < 4; ++reg) {
                int row = m0 + wr * 32 + i * 16 + quad * 4 + reg;
                int col = n0 + wc * 32 + j * 16 + lq;
                out[(size_t)row * HID_ + col] =
                    acc[i][j][reg] + bias[col] + hidden[(size_t)row * HID_ + col];
            }
}

// ---------------------------------------------------------------------------
// RoPE + rescale v2 — vectorized: one thread = 8 rotation pairs.
// ---------------------------------------------------------------------------
__global__ __launch_bounds__(256)
void rope_kernel(const unsigned short* __restrict__ q, const unsigned short* __restrict__ k,
                 const float* __restrict__ cost, const float* __restrict__ sint,
                 unsigned short* __restrict__ qb, unsigned short* __restrict__ kb)
{
    const float QSCALE = 0.11180339887498949f * 1.4426950408889634f;  // 1/sqrt(80)*log2(e)
    int idx = blockIdx.x * 256 + threadIdx.x;   // over H*S*5
    const int total = H_ * S_ * 5;
    if (idx >= total) return;
    int j  = idx % 5;
    int hs = idx / 5;
    int s  = hs % S_;
    int d0 = j * 8;
    const unsigned short* qp = q + (size_t)hs * D_ + d0;
    const unsigned short* kp = k + (size_t)hs * D_ + d0;
    unsigned short* qo = qb + (size_t)hs * DP_ + d0;
    unsigned short* ko = kb + (size_t)hs * DP_ + d0;
    const float* cp = cost + s * D_ + d0;
    const float* sp = sint + s * D_ + d0;

    bf16x8 q1 = *(const bf16x8*)(qp);
    bf16x8 q2 = *(const bf16x8*)(qp + 40);
    bf16x8 k1 = *(const bf16x8*)(kp);
    bf16x8 k2 = *(const bf16x8*)(kp + 40);
    f32x4 c1[2] = { *(const f32x4*)(cp),      *(const f32x4*)(cp + 4)  };
    f32x4 c2[2] = { *(const f32x4*)(cp + 40), *(const f32x4*)(cp + 44) };
    f32x4 s1[2] = { *(const f32x4*)(sp),      *(const f32x4*)(sp + 4)  };
    f32x4 s2[2] = { *(const f32x4*)(sp + 40), *(const f32x4*)(sp + 44) };

    bf16x8 oq1, oq2, ok1, ok2;
    #pragma unroll
    for (int e = 0; e < 8; ++e) {
        float cc1 = c1[e >> 2][e & 3], ss1 = s1[e >> 2][e & 3];
        float cc2 = c2[e >> 2][e & 3], ss2 = s2[e >> 2][e & 3];
        float x1 = b2f((unsigned short)q1[e]), x2 = b2f((unsigned short)q2[e]);
        oq1[e] = (short)f2b((x1 * cc1 - x2 * ss1) * QSCALE);
        oq2[e] = (short)f2b((x2 * cc2 + x1 * ss2) * QSCALE);
        x1 = b2f((unsigned short)k1[e]); x2 = b2f((unsigned short)k2[e]);
        ok1[e] = (short)f2b(x1 * cc1 - x2 * ss1);
        ok2[e] = (short)f2b(x2 * cc2 + x1 * ss2);
    }
    *(bf16x8*)(qo)      = oq1;
    *(bf16x8*)(qo + 40) = oq2;
    *(bf16x8*)(ko)      = ok1;
    *(bf16x8*)(ko + 40) = ok2;
    if (j == 0) {
        uint4 z = {0u, 0u, 0u, 0u};
        *(uint4*)(qo + 80) = z;
        *(uint4*)(qo + 88) = z;
        *(uint4*)(ko + 80) = z;
        *(uint4*)(ko + 88) = z;
    }
}

// ---------------------------------------------------------------------------
// Flash attention v6 — K+V LDS double-buffer, stage-early, one barrier per
// round, s_setprio around MFMA clusters, hw exp2. (measured 94 us)
// ---------------------------------------------------------------------------
#define KBUF_ 16384
#define VBUF_ 10240
#define BUF_  26624    // KBUF_ + VBUF_

__global__ __launch_bounds__(256, 3)
void attn_kernel(const unsigned short* __restrict__ Qb,
                 const unsigned short* __restrict__ Kb,
                 const unsigned short* __restrict__ Vtb,
                 unsigned short* __restrict__ attnb)
{
    __shared__ __align__(16) unsigned char smem[2 * BUF_];

    int h   = blockIdx.y;
    int qb0 = blockIdx.x * 64;
    int t      = threadIdx.x;
    int wave   = t >> 6;
    int lane   = t & 63;
    int lq     = lane & 15;
    int quad   = lane >> 4;
    int qh     = wave & 1;
    int stripe = wave >> 1;
    int Q0     = qb0 + qh * 32;
    int swz    = (lq & 7) << 4;

    // Q fragments: 2 q-tiles x 3 k-chunks (B-operand of mfma(K,Q))
    bf16x8 qf[2][3];
    #pragma unroll
    for (int qt = 0; qt < 2; ++qt)
        #pragma unroll
        for (int kc = 0; kc < 3; ++kc)
            qf[qt][kc] = *(const bf16x8*)(Qb + ((size_t)h * S_ + Q0 + qt * 16 + lq) * DP_ + kc * 32 + quad * 8);

    f32x4 O[2][5];
    #pragma unroll
    for (int qt = 0; qt < 2; ++qt)
        #pragma unroll
        for (int dt = 0; dt < 5; ++dt) O[qt][dt] = (f32x4){0.f, 0.f, 0.f, 0.f};
    float l_acc[2] = {0.f, 0.f};

    // ---- staging descriptors (round-0 sources; advance by r * stride)
    const unsigned char* kS[4]; int kD[4];
    #pragma unroll
    for (int ii = 0; ii < 4; ++ii) {
        int i  = wave * 4 + ii;
        int rl = i * 4 + (lane >> 4);          // LDS row 0..63 == k-row within round
        kS[ii] = (const unsigned char*)(Kb + ((size_t)h * S_ + rl) * DP_)
               + (((lane & 15) * 16) ^ ((rl & 7) << 4));
        kD[ii] = i * 1024;
    }
    const unsigned char* vS[3]; int vD[3];
    int nv = (wave < 2) ? 3 : 2;
    #pragma unroll
    for (int jj = 0; jj < 3; ++jj) {
        int j = (jj < 2) ? (wave + jj * 4) : (8 + wave);
        int d = j * 8 + (lane >> 3);           // 0..79 (for used instrs)
        vS[jj] = (const unsigned char*)(Vtb + (size_t)(h * D_ + d) * S_)
               + (((lane & 7) * 16) ^ ((d & 7) << 4));
        vD[jj] = KBUF_ + j * 1024;
    }

    #define STAGE(bufoff, rr)                                                   \
        do {                                                                    \
            size_t kadv = (size_t)(rr) * (64 * DP_ * 2);                        \
            size_t vadv = (size_t)(rr) * 128;                                   \
            _Pragma("unroll")                                                   \
            for (int ii = 0; ii < 4; ++ii)                                      \
                gl16(kS[ii] + kadv, smem + (bufoff) + kD[ii]);                  \
            _Pragma("unroll")                                                   \
            for (int jj = 0; jj < 3; ++jj)                                      \
                if (jj < nv) gl16(vS[jj] + vadv, smem + (bufoff) + vD[jj]);     \
        } while (0)

    // ---- prologue: stage round 0
    STAGE(0, 0);
    asm volatile("s_waitcnt vmcnt(0)" ::: "memory");
    __syncthreads();

    int cur = 0;
    for (int r = 0; r < 49; ++r) {
        if (r < 48) STAGE(cur ^ BUF_, r + 1);

        const unsigned char* Kbase = smem + cur;
        const unsigned char* Vbase = Kbase + KBUF_;

        // ---- QK^T (swapped: mfma(K,Q)); own 32-k stripe = 2 kt tiles
        f32x4 sc[2][2];
        __builtin_amdgcn_s_setprio(1);
        #pragma unroll
        for (int kt = 0; kt < 2; ++kt) {
            const unsigned char* kbp = Kbase + (stripe * 32 + kt * 16 + lq) * 256;
            bf16x8 kf0 = *(const bf16x8*)(kbp + ((  0 + quad * 16) ^ swz));
            bf16x8 kf1 = *(const bf16x8*)(kbp + (( 64 + quad * 16) ^ swz));
            bf16x8 kf2 = *(const bf16x8*)(kbp + ((128 + quad * 16) ^ swz));
            #pragma unroll
            for (int qt = 0; qt < 2; ++qt) {
                f32x4 a = (f32x4){0.f, 0.f, 0.f, 0.f};
                a = __builtin_amdgcn_mfma_f32_16x16x32_bf16(kf0, qf[qt][0], a, 0, 0, 0);
                a = __builtin_amdgcn_mfma_f32_16x16x32_bf16(kf1, qf[qt][1], a, 0, 0, 0);
                a = __builtin_amdgcn_mfma_f32_16x16x32_bf16(kf2, qf[qt][2], a, 0, 0, 0);
                sc[qt][kt] = a;
            }
        }
        __builtin_amdgcn_s_setprio(0);

        // ---- softmax numerator, fully in-register (hw exp2)
        union PaU { bf16x8 v8; unsigned int d[4]; } pa[2];
        #pragma unroll
        for (int qt = 0; qt < 2; ++qt) {
            float e00 = exp2_hw(sc[qt][0][0]), e01 = exp2_hw(sc[qt][0][1]);
            float e02 = exp2_hw(sc[qt][0][2]), e03 = exp2_hw(sc[qt][0][3]);
            float e10 = exp2_hw(sc[qt][1][0]), e11 = exp2_hw(sc[qt][1][1]);
            float e12 = exp2_hw(sc[qt][1][2]), e13 = exp2_hw(sc[qt][1][3]);
            l_acc[qt] += ((e00 + e01) + (e02 + e03)) + ((e10 + e11) + (e12 + e13));
            pa[qt].d[0] = cvt_pk_bf16(e00, e01);
            pa[qt].d[1] = cvt_pk_bf16(e02, e03);
            pa[qt].d[2] = cvt_pk_bf16(e10, e11);
            pa[qt].d[3] = cvt_pk_bf16(e12, e13);
        }

        // ---- PV with permuted K-dim: k_eff(quad,j) = stripe*32+(j>>2)*16+quad*4+(j&3)
        __builtin_amdgcn_s_setprio(1);
        #pragma unroll
        for (int dt = 0; dt < 5; ++dt) {
            const unsigned char* vbp = Vbase + (dt * 16 + lq) * 128;
            union { bf16x8 v8; bf16x4 v4[2]; } vv;
            vv.v4[0] = *(const bf16x4*)(vbp + ((stripe * 64 +      quad * 8) ^ swz));
            vv.v4[1] = *(const bf16x4*)(vbp + ((stripe * 64 + 32 + quad * 8) ^ swz));
            #pragma unroll
            for (int qt = 0; qt < 2; ++qt)
                O[qt][dt] = __builtin_amdgcn_mfma_f32_16x16x32_bf16(pa[qt].v8, vv.v8, O[qt][dt], 0, 0, 0);
        }
        __builtin_amdgcn_s_setprio(0);

        asm volatile("s_waitcnt vmcnt(0)" ::: "memory");
        __syncthreads();
        cur ^= BUF_;
    }
    #undef STAGE

    // ---- epilogue: cross-quad l reduce, cross-stripe O/l reduce via LDS
    float lr[2];
    #pragma unroll
    for (int qt = 0; qt < 2; ++qt) {
        float l = l_acc[qt];
        l += __shfl_xor(l, 16);
        l += __shfl_xor(l, 32);
        lr[qt] = l;                       // quad-uniform denom partial for (qt,lq)
    }
    f32x4* Of = (f32x4*)smem;             // [qh*2+qt][dt][lane]
    float* Lf = (float*)(smem + 20480);   // [qh*2+qt][16]
    if (stripe == 1) {
        #pragma unroll
        for (int qt = 0; qt < 2; ++qt) {
            #pragma unroll
            for (int dt = 0; dt < 5; ++dt)
                Of[((qh * 2 + qt) * 5 + dt) * 64 + lane] = O[qt][dt];
            if (lane < 16) Lf[(qh * 2 + qt) * 16 + lane] = lr[qt];
        }
    }
    __syncthreads();
    if (stripe == 0) {
        #pragma unroll
        for (int qt = 0; qt < 2; ++qt) {
            float ltot = lr[qt] + Lf[(qh * 2 + qt) * 16 + lq];
            #pragma unroll
            for (int dt = 0; dt < 5; ++dt)
                O[qt][dt] += Of[((qh * 2 + qt) * 5 + dt) * 64 + lane];
            #pragma unroll
            for (int reg = 0; reg < 4; ++reg) {
                float l = __shfl(ltot, quad * 4 + reg, 16);
                float linv = 1.0f / l;
                int s = Q0 + qt * 16 + quad * 4 + reg;
                unsigned short* orow = attnb + (size_t)s * HID_ + h * D_;
                #pragma unroll
                for (int dt = 0; dt < 5; ++dt)
                    orow[dt * 16 + lq] = f2b(O[qt][dt][reg] * linv);
            }
        }
    }
}

// ---------------------------------------------------------------------------
extern "C" void kernel_launch(void* const* d_in, const int* in_sizes, int n_in,
                              void* d_out, int out_size, void* d_ws, size_t ws_size,
                              hipStream_t stream)
{
    const float* hidden = (const float*)d_in[0];
    const float* x_norm = (const float*)d_in[1];
    const float* qkv_w  = (const float*)d_in[2];
    const float* qkv_b  = (const float*)d_in[3];
    const float* proj_w = (const float*)d_in[4];
    const float* proj_b = (const float*)d_in[5];
    const float* cost   = (const float*)d_in[6];
    const float* sint   = (const float*)d_in[7];
    float* out = (float*)d_out;

    unsigned short* w      = (unsigned short*)d_ws;
    unsigned short* qbuf   = w;                       // [H][S][80]  pre-rope q
    unsigned short* kbuf   = qbuf + 4014080;          // [H][S][80]  pre-rope k
    unsigned short* vtb    = kbuf + 4014080;          // [H][80][S]  v transposed (+16-row pad)
    unsigned short* kbb    = vtb + 4064256;           // [H][S][96]  roped k
    unsigned short* xb     = kbb + 4816896;           // [S][HID]    x_norm bf16
    unsigned short* wqkvb  = xb + 4014080;            // [3840][HID] qkv_w bf16
    unsigned short* wprojb = wqkvb + 4915200;         // [HID][HID]  proj_w bf16
    unsigned short* qbb    = wqkvb;                   // alias: roped q (wqkvb dead after qkv gemm)
    unsigned short* abuf   = qbuf;                    // alias: attn out (qbuf dead after rope)

    cast3_kernel<<<(N4_X + N4_Q + N4_P + 255) / 256, 256, 0, stream>>>(
        x_norm, xb, qkv_w, wqkvb, proj_w, wprojb);

    qkv_mfma_kernel<<<dim3(25, 30), 256, 0, stream>>>(xb, wqkvb, qkv_b, qbuf, kbuf, vtb);
    rope_kernel<<<(H_ * S_ * 5 + 255) / 256, 256, 0, stream>>>(qbuf, kbuf, cost, sint, qbb, kbb);
    attn_kernel<<<dim3(S_ / 64, H_), 256, 0, stream>>>(qbb, kbb, vtb, abuf);
    proj_mfma_kernel<<<dim3(49, 20), 256, 0, stream>>>(abuf, wprojb, proj_b, hidden, out);
}

// Round 8
// 298.884 us; speedup vs baseline: 1.0702x; 1.0084x over previous
//
#include <hip/hip_runtime.h>
#include <hip/hip_bf16.h>

#define S_   3136
#define H_   16
#define D_   80
#define DP_  96        // D padded to multiple of 32 for MFMA K-dim
#define HID_ 1280

typedef short  bf16x8 __attribute__((ext_vector_type(8)));
typedef short  bf16x4 __attribute__((ext_vector_type(4)));
typedef float  f32x4  __attribute__((ext_vector_type(4)));

__device__ __forceinline__ float b2f(unsigned short u) {
    union { unsigned int i; float f; } c;
    c.i = ((unsigned int)u) << 16;
    return c.f;
}
__device__ __forceinline__ unsigned short f2b(float f) {
    union { unsigned int i; float f; } c;
    c.f = f;
    unsigned int x = c.i;
    unsigned int lsb = (x >> 16) & 1u;
    x += 0x7fffu + lsb;   // round-to-nearest-even
    return (unsigned short)(x >> 16);
}
__device__ __forceinline__ unsigned int cvt_pk_bf16(float lo, float hi) {
    unsigned int r;
    asm("v_cvt_pk_bf16_f32 %0, %1, %2" : "=v"(r) : "v"(lo), "v"(hi));
    return r;
}
__device__ __forceinline__ float exp2_hw(float x) {
    float r;
    asm("v_exp_f32 %0, %1" : "=v"(r) : "v"(x));
    return r;
}

typedef const void __attribute__((address_space(1))) GAS;
typedef void __attribute__((address_space(3))) LAS;
__device__ __forceinline__ void gl16(const void* g, void* l) {
    __builtin_amdgcn_global_load_lds((GAS*)g, (LAS*)l, 16, 0, 0);
}

// ---------------------------------------------------------------------------
// merged fp32 -> bf16 cast for x_norm / qkv_w / proj_w (one launch)
// ---------------------------------------------------------------------------
#define N4_X 1003520
#define N4_Q 1228800
#define N4_P 409600

__global__ __launch_bounds__(256)
void cast3_kernel(const float* __restrict__ x0, unsigned short* __restrict__ y0,
                  const float* __restrict__ x1, unsigned short* __restrict__ y1,
                  const float* __restrict__ x2, unsigned short* __restrict__ y2)
{
    int i = blockIdx.x * 256 + threadIdx.x;
    const float* src; unsigned short* dst;
    if (i < N4_X)               { src = x0; dst = y0; }
    else if (i < N4_X + N4_Q)   { src = x1; dst = y1; i -= N4_X; }
    else if (i < N4_X + N4_Q + N4_P) { src = x2; dst = y2; i -= N4_X + N4_Q; }
    else return;
    float4 v = ((const float4*)src)[i];
    ushort4 o;
    o.x = f2b(v.x); o.y = f2b(v.y); o.z = f2b(v.z); o.w = f2b(v.w);
    ((ushort4*)dst)[i] = o;
}

// ---------------------------------------------------------------------------
// QKV GEMM (round-5 proven): 128x128 tile, BK=64 via DOUBLE-SLAB LDS,
// register-staged with full-iteration prefetch distance. 4 waves (2x2).
// ---------------------------------------------------------------------------
#define ASTR 40

__global__ __launch_bounds__(256)
void qkv_mfma_kernel(const unsigned short* __restrict__ Ab,
                     const unsigned short* __restrict__ Wb,
                     const float* __restrict__ bias,
                     unsigned short* __restrict__ qo, unsigned short* __restrict__ ko,
                     unsigned short* __restrict__ vtb)
{
    __shared__ __align__(16) short As[2][128][ASTR];
    __shared__ __align__(16) short Bs[2][128][ASTR];
    int m0 = blockIdx.x * 128;
    int n0 = blockIdx.y * 128;
    int t = threadIdx.x;
    int wave = t >> 6, lane = t & 63, lq = lane & 15, quad = lane >> 4;
    int wr = wave >> 1, wc = wave & 1;

    int r0  = t >> 2;
    int r1  = r0 + 64;
    int kc0 = (t & 3) << 3;
    const unsigned short* pa0 = Ab + (size_t)min(m0 + r0, S_ - 1) * HID_ + kc0;
    const unsigned short* pa1 = Ab + (size_t)min(m0 + r1, S_ - 1) * HID_ + kc0;
    const unsigned short* pb0 = Wb + (size_t)(n0 + r0) * HID_ + kc0;
    const unsigned short* pb1 = Wb + (size_t)(n0 + r1) * HID_ + kc0;

    const bf16x8* afp[2][4]; const bf16x8* bfp[2][4];
    #pragma unroll
    for (int s = 0; s < 2; ++s)
        #pragma unroll
        for (int i = 0; i < 4; ++i) {
            afp[s][i] = (const bf16x8*)&As[s][wr * 64 + i * 16 + lq][quad * 8];
            bfp[s][i] = (const bf16x8*)&Bs[s][wc * 64 + i * 16 + lq][quad * 8];
        }

    f32x4 acc[4][4];
    #pragma unroll
    for (int i = 0; i < 4; ++i)
        #pragma unroll
        for (int j = 0; j < 4; ++j) acc[i][j] = (f32x4){0.f, 0.f, 0.f, 0.f};

    bf16x8 va[2][2], vb[2][2];   // [slab][row-half]
    #pragma unroll
    for (int s = 0; s < 2; ++s) {
        va[s][0] = *(const bf16x8*)(pa0 + s * 32);
        va[s][1] = *(const bf16x8*)(pa1 + s * 32);
        vb[s][0] = *(const bf16x8*)(pb0 + s * 32);
        vb[s][1] = *(const bf16x8*)(pb1 + s * 32);
    }

    for (int kt = 0; kt < HID_; kt += 64) {
        __syncthreads();
        #pragma unroll
        for (int s = 0; s < 2; ++s) {
            *(bf16x8*)&As[s][r0][kc0] = va[s][0];
            *(bf16x8*)&As[s][r1][kc0] = va[s][1];
            *(bf16x8*)&Bs[s][r0][kc0] = vb[s][0];
            *(bf16x8*)&Bs[s][r1][kc0] = vb[s][1];
        }
        __syncthreads();
        if (kt + 64 < HID_) {
            #pragma unroll
            for (int s = 0; s < 2; ++s) {
                va[s][0] = *(const bf16x8*)(pa0 + kt + 64 + s * 32);
                va[s][1] = *(const bf16x8*)(pa1 + kt + 64 + s * 32);
                vb[s][0] = *(const bf16x8*)(pb0 + kt + 64 + s * 32);
                vb[s][1] = *(const bf16x8*)(pb1 + kt + 64 + s * 32);
            }
        }
        #pragma unroll
        for (int s = 0; s < 2; ++s) {
            bf16x8 af[4], bfr[4];
            #pragma unroll
            for (int i = 0; i < 4; ++i) af[i]  = *afp[s][i];
            #pragma unroll
            for (int j = 0; j < 4; ++j) bfr[j] = *bfp[s][j];
            #pragma unroll
            for (int i = 0; i < 4; ++i)
                #pragma unroll
                for (int j = 0; j < 4; ++j)
                    acc[i][j] = __builtin_amdgcn_mfma_f32_16x16x32_bf16(af[i], bfr[j], acc[i][j], 0, 0, 0);
        }
    }

    #pragma unroll
    for (int i = 0; i < 4; ++i)
        #pragma unroll
        for (int j = 0; j < 4; ++j)
            #pragma unroll
            for (int reg = 0; reg < 4; ++reg) {
                int row = m0 + wr * 64 + i * 16 + quad * 4 + reg;
                if (row >= S_) continue;
                int col = n0 + wc * 64 + j * 16 + lq;
                float val = acc[i][j][reg] + bias[col];
                int which = col / HID_;
                int rem   = col - which * HID_;
                int h     = rem / D_;
                int d     = rem - h * D_;
                if (which == 0)      qo[((size_t)h * S_ + row) * D_ + d] = f2b(val);
                else if (which == 1) ko[((size_t)h * S_ + row) * D_ + d] = f2b(val);
                else                 vtb[((size_t)h * D_ + d) * S_ + row] = f2b(val);
            }
}

// ---------------------------------------------------------------------------
// Proj GEMM v2 — 64x64 tile, QUAD-SLAB BK=128.
// ---------------------------------------------------------------------------
__global__ __launch_bounds__(256)
void proj_mfma_kernel(const unsigned short* __restrict__ Ab,
                      const unsigned short* __restrict__ Wb,
                      const float* __restrict__ bias, const float* __restrict__ hidden,
                      float* __restrict__ out)
{
    __shared__ __align__(16) short As[4][64][ASTR];
    __shared__ __align__(16) short Bs[4][64][ASTR];
    int m0 = blockIdx.x * 64;
    int n0 = blockIdx.y * 64;
    int t = threadIdx.x;
    int wave = t >> 6, lane = t & 63, lq = lane & 15, quad = lane >> 4;
    int wr = wave >> 1, wc = wave & 1;

    int r  = t >> 2;
    int kc0 = (t & 3) << 3;
    const unsigned short* pa = Ab + (size_t)(m0 + r) * HID_ + kc0;
    const unsigned short* pb = Wb + (size_t)(n0 + r) * HID_ + kc0;

    const bf16x8* afp[4][2]; const bf16x8* bfp[4][2];
    #pragma unroll
    for (int s = 0; s < 4; ++s)
        #pragma unroll
        for (int i = 0; i < 2; ++i) {
            afp[s][i] = (const bf16x8*)&As[s][wr * 32 + i * 16 + lq][quad * 8];
            bfp[s][i] = (const bf16x8*)&Bs[s][wc * 32 + i * 16 + lq][quad * 8];
        }

    f32x4 acc[2][2];
    #pragma unroll
    for (int i = 0; i < 2; ++i)
        #pragma unroll
        for (int j = 0; j < 2; ++j) acc[i][j] = (f32x4){0.f, 0.f, 0.f, 0.f};

    bf16x8 va[4], vb[4];
    #pragma unroll
    for (int s = 0; s < 4; ++s) {
        va[s] = *(const bf16x8*)(pa + s * 32);
        vb[s] = *(const bf16x8*)(pb + s * 32);
    }

    for (int kt = 0; kt < HID_; kt += 128) {
        __syncthreads();
        #pragma unroll
        for (int s = 0; s < 4; ++s) {
            *(bf16x8*)&As[s][r][kc0] = va[s];
            *(bf16x8*)&Bs[s][r][kc0] = vb[s];
        }
        __syncthreads();
        if (kt + 128 < HID_) {
            #pragma unroll
            for (int s = 0; s < 4; ++s) {
                va[s] = *(const bf16x8*)(pa + kt + 128 + s * 32);
                vb[s] = *(const bf16x8*)(pb + kt + 128 + s * 32);
            }
        }
        #pragma unroll
        for (int s = 0; s < 4; ++s) {
            bf16x8 af[2], bfr[2];
            #pragma unroll
            for (int i = 0; i < 2; ++i) af[i]  = *afp[s][i];
            #pragma unroll
            for (int j = 0; j < 2; ++j) bfr[j] = *bfp[s][j];
            #pragma unroll
            for (int i = 0; i < 2; ++i)
                #pragma unroll
                for (int j = 0; j < 2; ++j)
                    acc[i][j] = __builtin_amdgcn_mfma_f32_16x16x32_bf16(af[i], bfr[j], acc[i][j], 0, 0, 0);
        }
    }

    #pragma unroll
    for (int i = 0; i < 2; ++i)
        #pragma unroll
        for (int j = 0; j < 2; ++j)
            #pragma unroll
            for (int reg = 0; reg < 4; ++reg) {
                int row = m0 + wr * 32 + i * 16 + quad * 4 + reg;
                int col = n0 + wc * 32 + j * 16 + lq;
                out[(size_t)row * HID_ + col] =
                    acc[i][j][reg] + bias[col] + hidden[(size_t)row * HID_ + col];
            }
}

// ---------------------------------------------------------------------------
// RoPE + rescale v2 — vectorized: one thread = 8 rotation pairs.
// ---------------------------------------------------------------------------
__global__ __launch_bounds__(256)
void rope_kernel(const unsigned short* __restrict__ q, const unsigned short* __restrict__ k,
                 const float* __restrict__ cost, const float* __restrict__ sint,
                 unsigned short* __restrict__ qb, unsigned short* __restrict__ kb)
{
    const float QSCALE = 0.11180339887498949f * 1.4426950408889634f;  // 1/sqrt(80)*log2(e)
    int idx = blockIdx.x * 256 + threadIdx.x;   // over H*S*5
    const int total = H_ * S_ * 5;
    if (idx >= total) return;
    int j  = idx % 5;
    int hs = idx / 5;
    int s  = hs % S_;
    int d0 = j * 8;
    const unsigned short* qp = q + (size_t)hs * D_ + d0;
    const unsigned short* kp = k + (size_t)hs * D_ + d0;
    unsigned short* qo = qb + (size_t)hs * DP_ + d0;
    unsigned short* ko = kb + (size_t)hs * DP_ + d0;
    const float* cp = cost + s * D_ + d0;
    const float* sp = sint + s * D_ + d0;

    bf16x8 q1 = *(const bf16x8*)(qp);
    bf16x8 q2 = *(const bf16x8*)(qp + 40);
    bf16x8 k1 = *(const bf16x8*)(kp);
    bf16x8 k2 = *(const bf16x8*)(kp + 40);
    f32x4 c1[2] = { *(const f32x4*)(cp),      *(const f32x4*)(cp + 4)  };
    f32x4 c2[2] = { *(const f32x4*)(cp + 40), *(const f32x4*)(cp + 44) };
    f32x4 s1[2] = { *(const f32x4*)(sp),      *(const f32x4*)(sp + 4)  };
    f32x4 s2[2] = { *(const f32x4*)(sp + 40), *(const f32x4*)(sp + 44) };

    bf16x8 oq1, oq2, ok1, ok2;
    #pragma unroll
    for (int e = 0; e < 8; ++e) {
        float cc1 = c1[e >> 2][e & 3], ss1 = s1[e >> 2][e & 3];
        float cc2 = c2[e >> 2][e & 3], ss2 = s2[e >> 2][e & 3];
        float x1 = b2f((unsigned short)q1[e]), x2 = b2f((unsigned short)q2[e]);
        oq1[e] = (short)f2b((x1 * cc1 - x2 * ss1) * QSCALE);
        oq2[e] = (short)f2b((x2 * cc2 + x1 * ss2) * QSCALE);
        x1 = b2f((unsigned short)k1[e]); x2 = b2f((unsigned short)k2[e]);
        ok1[e] = (short)f2b(x1 * cc1 - x2 * ss1);
        ok2[e] = (short)f2b(x2 * cc2 + x1 * ss2);
    }
    *(bf16x8*)(qo)      = oq1;
    *(bf16x8*)(qo + 40) = oq2;
    *(bf16x8*)(ko)      = ok1;
    *(bf16x8*)(ko + 40) = ok2;
    if (j == 0) {
        uint4 z = {0u, 0u, 0u, 0u};
        *(uint4*)(qo + 80) = z;
        *(uint4*)(qo + 88) = z;
        *(uint4*)(ko + 80) = z;
        *(uint4*)(ko + 88) = z;
    }
}

// ---------------------------------------------------------------------------
// Flash attention v7 — TRIPLE-buffered K+V with counted vmcnt (T4).
// Stage round r+2 at the top of round r; end of round waits vmcnt(7): the
// 7 OLDEST outstanding loads (round r+1's, issued ~2 full rounds earlier)
// must be done, while r+2's 7 stay in flight across the barrier. The
// end-of-round drain (the residual stall of v6) disappears.
// LDS 3 x 26624 = 79872 B -> 2 blocks/CU.
// ---------------------------------------------------------------------------
#define KBUF_ 16384
#define VBUF_ 10240
#define BUF_  26624    // KBUF_ + VBUF_

__global__ __launch_bounds__(256, 2)
void attn_kernel(const unsigned short* __restrict__ Qb,
                 const unsigned short* __restrict__ Kb,
                 const unsigned short* __restrict__ Vtb,
                 unsigned short* __restrict__ attnb)
{
    __shared__ __align__(16) unsigned char smem[3 * BUF_];

    int h   = blockIdx.y;
    int qb0 = blockIdx.x * 64;
    int t      = threadIdx.x;
    int wave   = t >> 6;
    int lane   = t & 63;
    int lq     = lane & 15;
    int quad   = lane >> 4;
    int qh     = wave & 1;
    int stripe = wave >> 1;
    int Q0     = qb0 + qh * 32;
    int swz    = (lq & 7) << 4;

    // Q fragments: 2 q-tiles x 3 k-chunks (B-operand of mfma(K,Q))
    bf16x8 qf[2][3];
    #pragma unroll
    for (int qt = 0; qt < 2; ++qt)
        #pragma unroll
        for (int kc = 0; kc < 3; ++kc)
            qf[qt][kc] = *(const bf16x8*)(Qb + ((size_t)h * S_ + Q0 + qt * 16 + lq) * DP_ + kc * 32 + quad * 8);

    f32x4 O[2][5];
    #pragma unroll
    for (int qt = 0; qt < 2; ++qt)
        #pragma unroll
        for (int dt = 0; dt < 5; ++dt) O[qt][dt] = (f32x4){0.f, 0.f, 0.f, 0.f};
    float l_acc[2] = {0.f, 0.f};

    // ---- staging descriptors (round-0 sources; advance by r * stride)
    const unsigned char* kS[4]; int kD[4];
    #pragma unroll
    for (int ii = 0; ii < 4; ++ii) {
        int i  = wave * 4 + ii;
        int rl = i * 4 + (lane >> 4);          // LDS row 0..63 == k-row within round
        kS[ii] = (const unsigned char*)(Kb + ((size_t)h * S_ + rl) * DP_)
               + (((lane & 15) * 16) ^ ((rl & 7) << 4));
        kD[ii] = i * 1024;
    }
    const unsigned char* vS[3]; int vD[3];
    int nv = (wave < 2) ? 3 : 2;
    #pragma unroll
    for (int jj = 0; jj < 3; ++jj) {
        int j = (jj < 2) ? (wave + jj * 4) : (8 + wave);
        int d = j * 8 + (lane >> 3);           // 0..79 (for used instrs)
        vS[jj] = (const unsigned char*)(Vtb + (size_t)(h * D_ + d) * S_)
               + (((lane & 7) * 16) ^ ((d & 7) << 4));
        vD[jj] = KBUF_ + j * 1024;
    }

    #define STAGE(bufoff, rr)                                                   \
        do {                                                                    \
            size_t kadv = (size_t)(rr) * (64 * DP_ * 2);                        \
            size_t vadv = (size_t)(rr) * 128;                                   \
            _Pragma("unroll")                                                   \
            for (int ii = 0; ii < 4; ++ii)                                      \
                gl16(kS[ii] + kadv, smem + (bufoff) + kD[ii]);                  \
            _Pragma("unroll")                                                   \
            for (int jj = 0; jj < 3; ++jj)                                      \
                if (jj < nv) gl16(vS[jj] + vadv, smem + (bufoff) + vD[jj]);     \
        } while (0)

    // ---- prologue: stage rounds 0 and 1; wait for round 0 only
    STAGE(0,    0);
    STAGE(BUF_, 1);
    asm volatile("s_waitcnt vmcnt(7)" ::: "memory");
    __syncthreads();

    // ---- per-round body; CUROFF = buf[r%3], STGOFF = buf[(r+2)%3]
    #define BODY(CUROFF, STGOFF, RVAL)                                          \
    {                                                                           \
        int r_ = (RVAL);                                                        \
        if (r_ <= 46) STAGE((STGOFF), r_ + 2);                                  \
        const unsigned char* Kbase = smem + (CUROFF);                           \
        const unsigned char* Vbase = Kbase + KBUF_;                             \
        f32x4 sc[2][2];                                                         \
        __builtin_amdgcn_s_setprio(1);                                          \
        _Pragma("unroll")                                                       \
        for (int kt = 0; kt < 2; ++kt) {                                        \
            const unsigned char* kbp = Kbase + (stripe * 32 + kt * 16 + lq) * 256; \
            bf16x8 kf0 = *(const bf16x8*)(kbp + ((  0 + quad * 16) ^ swz));     \
            bf16x8 kf1 = *(const bf16x8*)(kbp + (( 64 + quad * 16) ^ swz));     \
            bf16x8 kf2 = *(const bf16x8*)(kbp + ((128 + quad * 16) ^ swz));     \
            _Pragma("unroll")                                                   \
            for (int qt = 0; qt < 2; ++qt) {                                    \
                f32x4 a = (f32x4){0.f, 0.f, 0.f, 0.f};                          \
                a = __builtin_amdgcn_mfma_f32_16x16x32_bf16(kf0, qf[qt][0], a, 0, 0, 0); \
                a = __builtin_amdgcn_mfma_f32_16x16x32_bf16(kf1, qf[qt][1], a, 0, 0, 0); \
                a = __builtin_amdgcn_mfma_f32_16x16x32_bf16(kf2, qf[qt][2], a, 0, 0, 0); \
                sc[qt][kt] = a;                                                 \
            }                                                                   \
        }                                                                       \
        __builtin_amdgcn_s_setprio(0);                                          \
        union PaU { bf16x8 v8; unsigned int d[4]; } pa[2];                      \
        _Pragma("unroll")                                                       \
        for (int qt = 0; qt < 2; ++qt) {                                        \
            float e00 = exp2_hw(sc[qt][0][0]), e01 = exp2_hw(sc[qt][0][1]);     \
            float e02 = exp2_hw(sc[qt][0][2]), e03 = exp2_hw(sc[qt][0][3]);     \
            float e10 = exp2_hw(sc[qt][1][0]), e11 = exp2_hw(sc[qt][1][1]);     \
            float e12 = exp2_hw(sc[qt][1][2]), e13 = exp2_hw(sc[qt][1][3]);     \
            l_acc[qt] += ((e00 + e01) + (e02 + e03)) + ((e10 + e11) + (e12 + e13)); \
            pa[qt].d[0] = cvt_pk_bf16(e00, e01);                                \
            pa[qt].d[1] = cvt_pk_bf16(e02, e03);                                \
            pa[qt].d[2] = cvt_pk_bf16(e10, e11);                                \
            pa[qt].d[3] = cvt_pk_bf16(e12, e13);                                \
        }                                                                       \
        __builtin_amdgcn_s_setprio(1);                                          \
        _Pragma("unroll")                                                       \
        for (int dt = 0; dt < 5; ++dt) {                                        \
            const unsigned char* vbp = Vbase + (dt * 16 + lq) * 128;            \
            union { bf16x8 v8; bf16x4 v4[2]; } vv;                              \
            vv.v4[0] = *(const bf16x4*)(vbp + ((stripe * 64 +      quad * 8) ^ swz)); \
            vv.v4[1] = *(const bf16x4*)(vbp + ((stripe * 64 + 32 + quad * 8) ^ swz)); \
            _Pragma("unroll")                                                   \
            for (int qt = 0; qt < 2; ++qt)                                      \
                O[qt][dt] = __builtin_amdgcn_mfma_f32_16x16x32_bf16(pa[qt].v8, vv.v8, O[qt][dt], 0, 0, 0); \
        }                                                                       \
        __builtin_amdgcn_s_setprio(0);                                          \
        if (r_ <= 46)      { asm volatile("s_waitcnt vmcnt(7)" ::: "memory"); } \
        else if (r_ == 47) { asm volatile("s_waitcnt vmcnt(0)" ::: "memory"); } \
        __syncthreads();                                                        \
    }

    // 49 rounds = 16 x 3 + 1; buffer cycle (r%3, (r+2)%3):
    for (int rr = 0; rr < 16; ++rr) {
        BODY(0,        2 * BUF_, rr * 3    );
        BODY(BUF_,     0,        rr * 3 + 1);
        BODY(2 * BUF_, BUF_,     rr * 3 + 2);
    }
    BODY(0, 2 * BUF_, 48);
    #undef BODY
    #undef STAGE

    // ---- epilogue: cross-quad l reduce, cross-stripe O/l reduce via LDS
    float lr[2];
    #pragma unroll
    for (int qt = 0; qt < 2; ++qt) {
        float l = l_acc[qt];
        l += __shfl_xor(l, 16);
        l += __shfl_xor(l, 32);
        lr[qt] = l;                       // quad-uniform denom partial for (qt,lq)
    }
    f32x4* Of = (f32x4*)smem;             // [qh*2+qt][dt][lane]
    float* Lf = (float*)(smem + 20480);   // [qh*2+qt][16]
    if (stripe == 1) {
        #pragma unroll
        for (int qt = 0; qt < 2; ++qt) {
            #pragma unroll
            for (int dt = 0; dt < 5; ++dt)
                Of[((qh * 2 + qt) * 5 + dt) * 64 + lane] = O[qt][dt];
            if (lane < 16) Lf[(qh * 2 + qt) * 16 + lane] = lr[qt];
        }
    }
    __syncthreads();
    if (stripe == 0) {
        #pragma unroll
        for (int qt = 0; qt < 2; ++qt) {
            float ltot = lr[qt] + Lf[(qh * 2 + qt) * 16 + lq];
            #pragma unroll
            for (int dt = 0; dt < 5; ++dt)
                O[qt][dt] += Of[((qh * 2 + qt) * 5 + dt) * 64 + lane];
            #pragma unroll
            for (int reg = 0; reg < 4; ++reg) {
                float l = __shfl(ltot, quad * 4 + reg, 16);
                float linv = 1.0f / l;
                int s = Q0 + qt * 16 + quad * 4 + reg;
                unsigned short* orow = attnb + (size_t)s * HID_ + h * D_;
                #pragma unroll
                for (int dt = 0; dt < 5; ++dt)
                    orow[dt * 16 + lq] = f2b(O[qt][dt][reg] * linv);
            }
        }
    }
}

// ---------------------------------------------------------------------------
extern "C" void kernel_launch(void* const* d_in, const int* in_sizes, int n_in,
                              void* d_out, int out_size, void* d_ws, size_t ws_size,
                              hipStream_t stream)
{
    const float* hidden = (const float*)d_in[0];
    const float* x_norm = (const float*)d_in[1];
    const float* qkv_w  = (const float*)d_in[2];
    const float* qkv_b  = (const float*)d_in[3];
    const float* proj_w = (const float*)d_in[4];
    const float* proj_b = (const float*)d_in[5];
    const float* cost   = (const float*)d_in[6];
    const float* sint   = (const float*)d_in[7];
    float* out = (float*)d_out;

    unsigned short* w      = (unsigned short*)d_ws;
    unsigned short* qbuf   = w;                       // [H][S][80]  pre-rope q
    unsigned short* kbuf   = qbuf + 4014080;          // [H][S][80]  pre-rope k
    unsigned short* vtb    = kbuf + 4014080;          // [H][80][S]  v transposed (+16-row pad)
    unsigned short* kbb    = vtb + 4064256;           // [H][S][96]  roped k
    unsigned short* xb     = kbb + 4816896;           // [S][HID]    x_norm bf16
    unsigned short* wqkvb  = xb + 4014080;            // [3840][HID] qkv_w bf16
    unsigned short* wprojb = wqkvb + 4915200;         // [HID][HID]  proj_w bf16
    unsigned short* qbb    = wqkvb;                   // alias: roped q (wqkvb dead after qkv gemm)
    unsigned short* abuf   = qbuf;                    // alias: attn out (qbuf dead after rope)

    cast3_kernel<<<(N4_X + N4_Q + N4_P + 255) / 256, 256, 0, stream>>>(
        x_norm, xb, qkv_w, wqkvb, proj_w, wprojb);

    qkv_mfma_kernel<<<dim3(25, 30), 256, 0, stream>>>(xb, wqkvb, qkv_b, qbuf, kbuf, vtb);
    rope_kernel<<<(H_ * S_ * 5 + 255) / 256, 256, 0, stream>>>(qbuf, kbuf, cost, sint, qbb, kbb);
    attn_kernel<<<dim3(S_ / 64, H_), 256, 0, stream>>>(qbb, kbb, vtb, abuf);
    proj_mfma_kernel<<<dim3(49, 20), 256, 0, stream>>>(abuf, wprojb, proj_b, hidden, out);
}